// Round 1
// baseline (10814.539 us; speedup 1.0000x reference)
//
#include <hip/hip_runtime.h>
#include <hip/hip_bf16.h>
#include <math.h>

// Tree constants
#define NC 8          // children per node
#define EMB 64        // E
#define HID 512       // H
#define WCW_LD 576    // E + H, leading dim of Wc_w rows

// GEMM tile config
#define BM 32
#define BN 32
#define BK 16

// ---------------------------------------------------------------------------
// Pe[v][j] = sum_k emb[v][k] * Wc_w[j][k]  + Wc_b[j]   (Wc_e part, bias folded)
// grid: (20), block: (512)
__global__ void pe_kernel(const float* __restrict__ emb, const float* __restrict__ Wc_w,
                          const float* __restrict__ Wc_b, float* __restrict__ Pe) {
    int v = blockIdx.x;
    int j = threadIdx.x;
    __shared__ float e[EMB];
    if (threadIdx.x < EMB) e[threadIdx.x] = emb[v * EMB + threadIdx.x];
    __syncthreads();
    float acc = Wc_b[j];
    const float* w = Wc_w + (long long)j * WCW_LD;   // Wc_e = Wc_w[:, :64]
#pragma unroll 8
    for (int k = 0; k < EMB; ++k) acc += e[k] * w[k];
    Pe[v * HID + j] = acc;
}

// ---------------------------------------------------------------------------
// Leaf level: h[i][j] = tanh(Pe[nt[4681+i]][j])
// grid: 32768*512/256 blocks, block 256
__global__ void leaf_kernel(const int* __restrict__ nt, const float* __restrict__ Pe,
                            float* __restrict__ h) {
    long long idx = (long long)blockIdx.x * blockDim.x + threadIdx.x;
    int i = (int)(idx >> 9);
    int j = (int)(idx & 511);
    int tv = nt[4681 + i];
    h[idx] = tanhf(Pe[tv * HID + j]);
}

// ---------------------------------------------------------------------------
// One GRU step, fused: computes for each (parent p, unit j)
//   xr,xz,xn (from x_t = child[p*8+t]) and hr,hz,hn (from hsrc[p]) via 6 dots,
//   then the GRU update -> hdst.
// grid: (ceil(n/BM), HID/BN), block 256 (16x16, 2x2 outputs/thread)
__global__ void gru_step_kernel(const float* __restrict__ child, int t,
                                const float* __restrict__ hsrc, float* __restrict__ hdst,
                                const float* __restrict__ W_ih, const float* __restrict__ W_hh,
                                const float* __restrict__ b_ih, const float* __restrict__ b_hh,
                                int n) {
    __shared__ float xs[BK][BM + 1];
    __shared__ float hs[BK][BM + 1];
    __shared__ float ws[6][BK][BN + 1];

    int p0 = blockIdx.x * BM;
    int j0 = blockIdx.y * BN;
    int tid = threadIdx.x;
    int tm = tid >> 4;        // 0..15
    int tn = tid & 15;        // 0..15

    float acc[6][2][2];
#pragma unroll
    for (int g = 0; g < 6; ++g)
#pragma unroll
        for (int a = 0; a < 2; ++a)
#pragma unroll
            for (int b = 0; b < 2; ++b) acc[g][a][b] = 0.f;

    for (int k0 = 0; k0 < HID; k0 += BK) {
        // load x and h tiles (BM x BK each), stored K-major
#pragma unroll
        for (int l = 0; l < 2; ++l) {
            int e = tid + l * 256;
            int r = e >> 4;       // parent row in tile
            int c = e & 15;       // k
            int p = p0 + r;
            float xv = 0.f, hv = 0.f;
            if (p < n) {
                xv = child[((long long)(p * NC + t)) * HID + k0 + c];
                hv = hsrc[(long long)p * HID + k0 + c];
            }
            xs[c][r] = xv;
            hs[c][r] = hv;
        }
        // load 6 weight tiles (BN x BK each): g=0..2 -> W_ih rows g*H+j ; 3..5 -> W_hh
#pragma unroll
        for (int g = 0; g < 3; ++g) {
#pragma unroll
            for (int l = 0; l < 2; ++l) {
                int e = tid + l * 256;
                int r = e >> 4;   // j row in tile
                int c = e & 15;   // k
                int j = j0 + r;
                ws[g][c][r]     = W_ih[((long long)(g * HID + j)) * HID + k0 + c];
                ws[3 + g][c][r] = W_hh[((long long)(g * HID + j)) * HID + k0 + c];
            }
        }
        __syncthreads();
#pragma unroll
        for (int kk = 0; kk < BK; ++kk) {
            float xv[2], hv[2];
            xv[0] = xs[kk][tm * 2];     xv[1] = xs[kk][tm * 2 + 1];
            hv[0] = hs[kk][tm * 2];     hv[1] = hs[kk][tm * 2 + 1];
            float wv[6][2];
#pragma unroll
            for (int g = 0; g < 6; ++g) {
                wv[g][0] = ws[g][kk][tn * 2];
                wv[g][1] = ws[g][kk][tn * 2 + 1];
            }
#pragma unroll
            for (int a = 0; a < 2; ++a)
#pragma unroll
                for (int b = 0; b < 2; ++b) {
                    acc[0][a][b] += xv[a] * wv[0][b];
                    acc[1][a][b] += xv[a] * wv[1][b];
                    acc[2][a][b] += xv[a] * wv[2][b];
                    acc[3][a][b] += hv[a] * wv[3][b];
                    acc[4][a][b] += hv[a] * wv[4][b];
                    acc[5][a][b] += hv[a] * wv[5][b];
                }
        }
        __syncthreads();
    }

    // epilogue: GRU update
#pragma unroll
    for (int a = 0; a < 2; ++a) {
        int p = p0 + tm * 2 + a;
        if (p >= n) continue;
#pragma unroll
        for (int b = 0; b < 2; ++b) {
            int j = j0 + tn * 2 + b;
            float xr = acc[0][a][b] + b_ih[j];
            float xz = acc[1][a][b] + b_ih[HID + j];
            float xn = acc[2][a][b] + b_ih[2 * HID + j];
            float hr = acc[3][a][b] + b_hh[j];
            float hz = acc[4][a][b] + b_hh[HID + j];
            float hn = acc[5][a][b] + b_hh[2 * HID + j];
            float r = 1.f / (1.f + expf(-(xr + hr)));
            float z = 1.f / (1.f + expf(-(xz + hz)));
            float cand = tanhf(xn + r * hn);
            float hprev = hsrc[(long long)p * HID + j];
            hdst[(long long)p * HID + j] = (1.f - z) * cand + z * hprev;
        }
    }
}

// ---------------------------------------------------------------------------
// Combine: hout[p][j] = tanh(Pe[nt[off+p]][j] + sum_k enc[p][k] * Wc_h[j][k])
// Wc_h[j][k] = Wc_w[j*576 + 64 + k]
// grid: (ceil(n/BM), HID/BN), block 256
__global__ void combine_kernel(const float* __restrict__ enc, const float* __restrict__ Wc_w,
                               const int* __restrict__ nt, int off,
                               const float* __restrict__ Pe, float* __restrict__ hout,
                               int n) {
    __shared__ float es[BK][BM + 1];
    __shared__ float ws[BK][BN + 1];

    int p0 = blockIdx.x * BM;
    int j0 = blockIdx.y * BN;
    int tid = threadIdx.x;
    int tm = tid >> 4;
    int tn = tid & 15;

    float acc[2][2] = {{0.f, 0.f}, {0.f, 0.f}};

    for (int k0 = 0; k0 < HID; k0 += BK) {
#pragma unroll
        for (int l = 0; l < 2; ++l) {
            int e = tid + l * 256;
            int r = e >> 4;
            int c = e & 15;
            int p = p0 + r;
            es[c][r] = (p < n) ? enc[(long long)p * HID + k0 + c] : 0.f;
            int j = j0 + r;
            ws[c][r] = Wc_w[(long long)j * WCW_LD + EMB + k0 + c];
        }
        __syncthreads();
#pragma unroll
        for (int kk = 0; kk < BK; ++kk) {
            float ev[2], wv[2];
            ev[0] = es[kk][tm * 2];  ev[1] = es[kk][tm * 2 + 1];
            wv[0] = ws[kk][tn * 2];  wv[1] = ws[kk][tn * 2 + 1];
#pragma unroll
            for (int a = 0; a < 2; ++a)
#pragma unroll
                for (int b = 0; b < 2; ++b) acc[a][b] += ev[a] * wv[b];
        }
        __syncthreads();
    }

#pragma unroll
    for (int a = 0; a < 2; ++a) {
        int p = p0 + tm * 2 + a;
        if (p >= n) continue;
        int tv = nt[off + p];
#pragma unroll
        for (int b = 0; b < 2; ++b) {
            int j = j0 + tn * 2 + b;
            hout[(long long)p * HID + j] = tanhf(Pe[tv * HID + j] + acc[a][b]);
        }
    }
}

// ---------------------------------------------------------------------------
extern "C" void kernel_launch(void* const* d_in, const int* in_sizes, int n_in,
                              void* d_out, int out_size, void* d_ws, size_t ws_size,
                              hipStream_t stream) {
    const int*   nt   = (const int*)d_in[0];
    const float* emb  = (const float*)d_in[1];
    const float* Wc_w = (const float*)d_in[2];
    const float* Wc_b = (const float*)d_in[3];
    const float* W_ih = (const float*)d_in[4];
    const float* W_hh = (const float*)d_in[5];
    const float* b_ih = (const float*)d_in[6];
    const float* b_hh = (const float*)d_in[7];
    float* out = (float*)d_out;

    // workspace layout (floats)
    float* ws_f = (float*)d_ws;
    float* Pe  = ws_f;                        // 20*512
    float* hA  = Pe + 20 * HID;               // 32768*512
    float* hB  = hA + 32768 * (long long)HID; // 4096*512
    float* hwA = hB + 4096 * (long long)HID;  // 4096*512
    float* hwB = hwA + 4096 * (long long)HID; // 4096*512

    pe_kernel<<<20, 512, 0, stream>>>(emb, Wc_w, Wc_b, Pe);
    leaf_kernel<<<(32768 * 512) / 256, 256, 0, stream>>>(nt, Pe, hA);

    const int sizes[5] = {1, 8, 64, 512, 4096};
    const int offs[5]  = {0, 1, 9, 73, 585};

    float* childbuf = hA;
    for (int d = 4; d >= 0; --d) {
        int n = sizes[d];
        hipMemsetAsync(hwA, 0, (size_t)n * HID * sizeof(float), stream);
        dim3 grid((n + BM - 1) / BM, HID / BN);
        for (int t = 0; t < NC; ++t) {
            const float* src = (t & 1) ? hwB : hwA;
            float*       dst = (t & 1) ? hwA : hwB;
            gru_step_kernel<<<grid, 256, 0, stream>>>(childbuf, t, src, dst,
                                                      W_ih, W_hh, b_ih, b_hh, n);
        }
        // after t=7 (odd), result is in hwA
        float* parent = (d == 0) ? out : ((d & 1) ? hA : hB);
        combine_kernel<<<grid, 256, 0, stream>>>(hwA, Wc_w, nt, offs[d], Pe, parent, n);
        childbuf = parent;
    }
}

// Round 2
// 1501.141 us; speedup vs baseline: 7.2042x; 7.2042x over previous
//
#include <hip/hip_runtime.h>
#include <hip/hip_bf16.h>
#include <math.h>

#define HID 512
#define WCW_LD 576

typedef unsigned short u16;
typedef __attribute__((ext_vector_type(8))) short bf16x8;
typedef __attribute__((ext_vector_type(4))) float f32x4;

__device__ __forceinline__ u16 f2bf(float f) {
    union { float f; unsigned u; } x; x.f = f;
    unsigned r = x.u + 0x7fffu + ((x.u >> 16) & 1u);
    return (u16)(r >> 16);
}
__device__ __forceinline__ float sigm(float x) { return 1.f / (1.f + expf(-x)); }

// ---- swizzled 64x64 bf16 LDS tile helpers (row stride 128 B, XOR 16B chunks) ----
__device__ __forceinline__ int lds_off(int row, int kbyte) {
    return row * 128 + (kbyte ^ ((row & 7) << 4));
}

// stage 64 rows x 64 cols (bf16) from row-major global; rows >= nrows -> zeros
__device__ __forceinline__ void stage_tile(uint8_t* lds, const u16* __restrict__ src,
                                           int row0, int nrows, long long stride, int k0, int tid) {
#pragma unroll
    for (int l = 0; l < 2; ++l) {
        int e = tid + l * 256;
        int r = e >> 3, c = e & 7;
        uint4 v = make_uint4(0u, 0u, 0u, 0u);
        if (row0 + r < nrows)
            v = *(const uint4*)(src + (long long)(row0 + r) * stride + k0 + c * 8);
        *(uint4*)(lds + lds_off(r, c * 16)) = v;
    }
}

__device__ __forceinline__ bf16x8 read_frag(const uint8_t* lds, int row, int kbyte) {
    return *(const bf16x8*)(lds + lds_off(row, kbyte));
}

// ---------------------------------------------------------------------------
// Pe[v][j] = emb[v] . Wc_e[j] + Wc_b[j]   (fp32, tiny: 20x512)
__global__ void pe_kernel(const float* __restrict__ emb, const float* __restrict__ Wc_w,
                          const float* __restrict__ Wc_b, float* __restrict__ Pe) {
    int v = blockIdx.x, j = threadIdx.x;
    __shared__ float e[64];
    if (threadIdx.x < 64) e[threadIdx.x] = emb[v * 64 + threadIdx.x];
    __syncthreads();
    float acc = Wc_b[j];
    const float* w = Wc_w + (long long)j * WCW_LD;
#pragma unroll 8
    for (int k = 0; k < 64; ++k) acc += e[k] * w[k];
    Pe[v * HID + j] = acc;
}

// ---------------------------------------------------------------------------
// Convert weights to bf16 once (reused ~45x)
__global__ void conv_w_kernel(const float* __restrict__ W_ih, const float* __restrict__ W_hh,
                              const float* __restrict__ Wc_w,
                              u16* __restrict__ Wih16, u16* __restrict__ Whh16,
                              u16* __restrict__ Wch16) {
    int idx = blockIdx.x * blockDim.x + threadIdx.x;
    int stride = gridDim.x * blockDim.x;
    for (int i = idx; i < 3 * HID * HID; i += stride) {
        Wih16[i] = f2bf(W_ih[i]);
        Whh16[i] = f2bf(W_hh[i]);
    }
    for (int i = idx; i < HID * HID; i += stride) {
        int j = i >> 9, k = i & 511;
        Wch16[i] = f2bf(Wc_w[(long long)j * WCW_LD + 64 + k]);
    }
}

// ---------------------------------------------------------------------------
// Leaf: h16[i][j] = bf16(tanh(Pe[nt[4681+i]][j])); 8 elems/thread
__global__ void leaf_kernel(const int* __restrict__ nt, const float* __restrict__ Pe,
                            u16* __restrict__ h16) {
    int e = blockIdx.x * blockDim.x + threadIdx.x;   // 32768*64 total
    int i = e >> 6, c = e & 63;
    int tv = nt[4681 + i];
    const float4* src = (const float4*)(Pe + (long long)tv * HID + c * 8);
    float4 a = src[0], b = src[1];
    u16 o0 = f2bf(tanhf(a.x)), o1 = f2bf(tanhf(a.y)), o2 = f2bf(tanhf(a.z)), o3 = f2bf(tanhf(a.w));
    u16 o4 = f2bf(tanhf(b.x)), o5 = f2bf(tanhf(b.y)), o6 = f2bf(tanhf(b.z)), o7 = f2bf(tanhf(b.w));
    uint4 v;
    v.x = (unsigned)o0 | ((unsigned)o1 << 16);
    v.y = (unsigned)o2 | ((unsigned)o3 << 16);
    v.z = (unsigned)o4 | ((unsigned)o5 << 16);
    v.w = (unsigned)o6 | ((unsigned)o7 << 16);
    *(uint4*)(h16 + (long long)i * HID + c * 8) = v;
}

// ---------------------------------------------------------------------------
// One fused GRU step: 6 gate GEMMs (x-side + h-side) in bf16 MFMA + GRU update.
// Block: 64 parents x 64 units, 4 waves (2x2), 32x32 per wave per gate.
__global__ __launch_bounds__(256, 2)
void gru_step_mfma(const u16* __restrict__ child, int t,
                   const float* __restrict__ hsrc_f, const u16* __restrict__ hsrc16,
                   float* __restrict__ hdst_f, u16* __restrict__ hdst16,
                   const u16* __restrict__ Wih16, const u16* __restrict__ Whh16,
                   const float* __restrict__ b_ih, const float* __restrict__ b_hh,
                   int n, int has_h) {
    __shared__ __align__(16) uint8_t sm[8][8192];   // Ax, Ah, Bih[3], Bhh[3]
    int tid = threadIdx.x;
    int p0 = blockIdx.x * 64, j0 = blockIdx.y * 64;
    int lane = tid & 63, w = tid >> 6, wr = w >> 1, wc = w & 1;

    f32x4 acc[6][2][2];
#pragma unroll
    for (int g = 0; g < 6; ++g)
#pragma unroll
        for (int i = 0; i < 2; ++i)
#pragma unroll
            for (int j = 0; j < 2; ++j) acc[g][i][j] = (f32x4){0.f, 0.f, 0.f, 0.f};

    for (int kt = 0; kt < 8; ++kt) {
        int k0 = kt * 64;
        stage_tile(sm[0], child + t * HID, p0, n, 8 * HID, k0, tid);
        if (has_h) stage_tile(sm[1], hsrc16, p0, n, HID, k0, tid);
#pragma unroll
        for (int g = 0; g < 3; ++g) {
            stage_tile(sm[2 + g], Wih16 + (long long)g * HID * HID, j0, 1 << 30, HID, k0, tid);
            if (has_h) stage_tile(sm[5 + g], Whh16 + (long long)g * HID * HID, j0, 1 << 30, HID, k0, tid);
        }
        __syncthreads();
#pragma unroll
        for (int s = 0; s < 2; ++s) {
            int kb = s * 64 + ((lane >> 4) << 4);
            bf16x8 ax0 = read_frag(sm[0], wr * 32 + (lane & 15), kb);
            bf16x8 ax1 = read_frag(sm[0], wr * 32 + 16 + (lane & 15), kb);
#pragma unroll
            for (int g = 0; g < 3; ++g) {
#pragma unroll
                for (int j = 0; j < 2; ++j) {
                    bf16x8 b = read_frag(sm[2 + g], wc * 32 + j * 16 + (lane & 15), kb);
                    acc[g][0][j] = __builtin_amdgcn_mfma_f32_16x16x32_bf16(ax0, b, acc[g][0][j], 0, 0, 0);
                    acc[g][1][j] = __builtin_amdgcn_mfma_f32_16x16x32_bf16(ax1, b, acc[g][1][j], 0, 0, 0);
                }
            }
            if (has_h) {
                bf16x8 ah0 = read_frag(sm[1], wr * 32 + (lane & 15), kb);
                bf16x8 ah1 = read_frag(sm[1], wr * 32 + 16 + (lane & 15), kb);
#pragma unroll
                for (int g = 0; g < 3; ++g) {
#pragma unroll
                    for (int j = 0; j < 2; ++j) {
                        bf16x8 b = read_frag(sm[5 + g], wc * 32 + j * 16 + (lane & 15), kb);
                        acc[3 + g][0][j] = __builtin_amdgcn_mfma_f32_16x16x32_bf16(ah0, b, acc[3 + g][0][j], 0, 0, 0);
                        acc[3 + g][1][j] = __builtin_amdgcn_mfma_f32_16x16x32_bf16(ah1, b, acc[3 + g][1][j], 0, 0, 0);
                    }
                }
            }
        }
        __syncthreads();
    }

    // epilogue: GRU update in fp32; C layout: col = lane&15, row = (lane>>4)*4 + q
#pragma unroll
    for (int i = 0; i < 2; ++i) {
#pragma unroll
        for (int j = 0; j < 2; ++j) {
            int jj = j0 + wc * 32 + j * 16 + (lane & 15);
            float bir = b_ih[jj], biz = b_ih[HID + jj], bin_ = b_ih[2 * HID + jj];
            float bhr = b_hh[jj], bhz = b_hh[HID + jj], bhn = b_hh[2 * HID + jj];
#pragma unroll
            for (int q = 0; q < 4; ++q) {
                int p = p0 + wr * 32 + i * 16 + (lane >> 4) * 4 + q;
                if (p >= n) continue;
                float xr = acc[0][i][j][q] + bir;
                float xz = acc[1][i][j][q] + biz;
                float xn = acc[2][i][j][q] + bin_;
                float hr = acc[3][i][j][q] + bhr;
                float hz = acc[4][i][j][q] + bhz;
                float hn = acc[5][i][j][q] + bhn;
                float r = sigm(xr + hr), z = sigm(xz + hz);
                float cand = tanhf(xn + r * hn);
                float hp = has_h ? hsrc_f[(long long)p * HID + jj] : 0.f;
                float hnew = (1.f - z) * cand + z * hp;
                hdst_f[(long long)p * HID + jj] = hnew;
                hdst16[(long long)p * HID + jj] = f2bf(hnew);
            }
        }
    }
}

// ---------------------------------------------------------------------------
// Combine: out[p][j] = tanh(Pe[nt[off+p]][j] + enc[p] . Wc_h[j])  (bf16 MFMA)
__global__ __launch_bounds__(256, 2)
void combine_mfma(const u16* __restrict__ enc16, const u16* __restrict__ Wch16,
                  const int* __restrict__ nt, int off, const float* __restrict__ Pe,
                  u16* __restrict__ out16, float* __restrict__ outf, int n) {
    __shared__ __align__(16) uint8_t sm[2][8192];
    int tid = threadIdx.x;
    int p0 = blockIdx.x * 64, j0 = blockIdx.y * 64;
    int lane = tid & 63, w = tid >> 6, wr = w >> 1, wc = w & 1;

    f32x4 acc[2][2];
#pragma unroll
    for (int i = 0; i < 2; ++i)
#pragma unroll
        for (int j = 0; j < 2; ++j) acc[i][j] = (f32x4){0.f, 0.f, 0.f, 0.f};

    for (int kt = 0; kt < 8; ++kt) {
        int k0 = kt * 64;
        stage_tile(sm[0], enc16, p0, n, HID, k0, tid);
        stage_tile(sm[1], Wch16, j0, 1 << 30, HID, k0, tid);
        __syncthreads();
#pragma unroll
        for (int s = 0; s < 2; ++s) {
            int kb = s * 64 + ((lane >> 4) << 4);
            bf16x8 a0 = read_frag(sm[0], wr * 32 + (lane & 15), kb);
            bf16x8 a1 = read_frag(sm[0], wr * 32 + 16 + (lane & 15), kb);
#pragma unroll
            for (int j = 0; j < 2; ++j) {
                bf16x8 b = read_frag(sm[1], wc * 32 + j * 16 + (lane & 15), kb);
                acc[0][j] = __builtin_amdgcn_mfma_f32_16x16x32_bf16(a0, b, acc[0][j], 0, 0, 0);
                acc[1][j] = __builtin_amdgcn_mfma_f32_16x16x32_bf16(a1, b, acc[1][j], 0, 0, 0);
            }
        }
        __syncthreads();
    }

#pragma unroll
    for (int i = 0; i < 2; ++i) {
#pragma unroll
        for (int j = 0; j < 2; ++j) {
            int jj = j0 + wc * 32 + j * 16 + (lane & 15);
#pragma unroll
            for (int q = 0; q < 4; ++q) {
                int p = p0 + wr * 32 + i * 16 + (lane >> 4) * 4 + q;
                if (p >= n) continue;
                int tv = nt[off + p];
                float v = tanhf(Pe[(long long)tv * HID + jj] + acc[i][j][q]);
                out16[(long long)p * HID + jj] = f2bf(v);
                if (outf) outf[(long long)p * HID + jj] = v;
            }
        }
    }
}

// ---------------------------------------------------------------------------
extern "C" void kernel_launch(void* const* d_in, const int* in_sizes, int n_in,
                              void* d_out, int out_size, void* d_ws, size_t ws_size,
                              hipStream_t stream) {
    const int*   nt   = (const int*)d_in[0];
    const float* emb  = (const float*)d_in[1];
    const float* Wc_w = (const float*)d_in[2];
    const float* Wc_b = (const float*)d_in[3];
    const float* W_ih = (const float*)d_in[4];
    const float* W_hh = (const float*)d_in[5];
    const float* b_ih = (const float*)d_in[6];
    const float* b_hh = (const float*)d_in[7];

    uint8_t* p = (uint8_t*)d_ws;
    u16*   cbA   = (u16*)p;   p += (size_t)32768 * HID * 2;   // leaf / level childs
    u16*   cbB   = (u16*)p;   p += (size_t)4096 * HID * 2;
    float* hwfA  = (float*)p; p += (size_t)4096 * HID * 4;    // fp32 h ping-pong
    float* hwfB  = (float*)p; p += (size_t)4096 * HID * 4;
    u16*   hw16A = (u16*)p;   p += (size_t)4096 * HID * 2;    // bf16 h ping-pong
    u16*   hw16B = (u16*)p;   p += (size_t)4096 * HID * 2;
    u16*   Wih16 = (u16*)p;   p += (size_t)3 * HID * HID * 2;
    u16*   Whh16 = (u16*)p;   p += (size_t)3 * HID * HID * 2;
    u16*   Wch16 = (u16*)p;   p += (size_t)HID * HID * 2;
    float* Pe    = (float*)p; p += (size_t)20 * HID * 4;

    conv_w_kernel<<<1024, 256, 0, stream>>>(W_ih, W_hh, Wc_w, Wih16, Whh16, Wch16);
    pe_kernel<<<20, 512, 0, stream>>>(emb, Wc_w, Wc_b, Pe);
    leaf_kernel<<<8192, 256, 0, stream>>>(nt, Pe, cbA);

    const int sizes[5] = {1, 8, 64, 512, 4096};
    const int offs[5]  = {0, 1, 9, 73, 585};

    const u16* child = cbA;
    for (int d = 4; d >= 0; --d) {
        int n = sizes[d];
        dim3 grid((n + 63) / 64, HID / 64);
        for (int t = 0; t < 8; ++t) {
            const float* sf  = (t & 1) ? hwfA : hwfB;   // src = buf[(t&1)^1]
            const u16*   s16 = (t & 1) ? hw16A : hw16B;
            float*       df  = (t & 1) ? hwfB : hwfA;   // dst = buf[t&1... t=0->A]
            u16*         d16 = (t & 1) ? hw16B : hw16A;
            gru_step_mfma<<<grid, 256, 0, stream>>>(child, t, sf, s16, df, d16,
                                                    Wih16, Whh16, b_ih, b_hh, n, t > 0);
        }
        // after t=7 result lives in hwfB/hw16B
        u16* cdst = (d & 1) ? cbA : cbB;
        combine_mfma<<<grid, 256, 0, stream>>>(hw16B, Wch16, nt, offs[d], Pe, cdst,
                                               (d == 0) ? (float*)d_out : (float*)0, n);
        child = cdst;
    }
}

// Round 3
// 1153.291 us; speedup vs baseline: 9.3771x; 1.3016x over previous
//
#include <hip/hip_runtime.h>
#include <hip/hip_bf16.h>
#include <math.h>

#define HID 512
#define WCW_LD 576

typedef unsigned short u16;
typedef __attribute__((ext_vector_type(8))) short bf16x8;
typedef __attribute__((ext_vector_type(4))) float f32x4;

__device__ __forceinline__ u16 f2bf(float f) {
    union { float f; unsigned u; } x; x.f = f;
    unsigned r = x.u + 0x7fffu + ((x.u >> 16) & 1u);
    return (u16)(r >> 16);
}
__device__ __forceinline__ float bf2f(u16 b) {
    union { unsigned u; float f; } x; x.u = ((unsigned)b) << 16; return x.f;
}
__device__ __forceinline__ float sigm(float x) { return 1.f / (1.f + expf(-x)); }

// ---- swizzled 64x64 bf16 LDS tile (row stride 128 B, XOR 16B chunks) ----
__device__ __forceinline__ int lds_off(int row, int kbyte) {
    return row * 128 + (kbyte ^ ((row & 7) << 4));
}
__device__ __forceinline__ void stage_tile(uint8_t* lds, const u16* __restrict__ src,
                                           int row0, int nrows, long long stride, int k0, int tid) {
#pragma unroll
    for (int l = 0; l < 2; ++l) {
        int e = tid + l * 256;
        int r = e >> 3, c = e & 7;
        uint4 v = make_uint4(0u, 0u, 0u, 0u);
        if (row0 + r < nrows)
            v = *(const uint4*)(src + (long long)(row0 + r) * stride + k0 + c * 8);
        *(uint4*)(lds + lds_off(r, c * 16)) = v;
    }
}
__device__ __forceinline__ bf16x8 read_frag(const uint8_t* lds, int row, int kbyte) {
    return *(const bf16x8*)(lds + lds_off(row, kbyte));
}

// ---------------------------------------------------------------------------
__global__ void pe_kernel(const float* __restrict__ emb, const float* __restrict__ Wc_w,
                          const float* __restrict__ Wc_b, float* __restrict__ Pe) {
    int v = blockIdx.x, j = threadIdx.x;
    __shared__ float e[64];
    if (threadIdx.x < 64) e[threadIdx.x] = emb[v * 64 + threadIdx.x];
    __syncthreads();
    float acc = Wc_b[j];
    const float* w = Wc_w + (long long)j * WCW_LD;
#pragma unroll 8
    for (int k = 0; k < 64; ++k) acc += e[k] * w[k];
    Pe[v * HID + j] = acc;
}

__global__ void conv_w_kernel(const float* __restrict__ W_ih, const float* __restrict__ W_hh,
                              const float* __restrict__ Wc_w,
                              u16* __restrict__ Wih16, u16* __restrict__ Whh16,
                              u16* __restrict__ Wch16) {
    int idx = blockIdx.x * blockDim.x + threadIdx.x;
    int stride = gridDim.x * blockDim.x;
    for (int i = idx; i < 3 * HID * HID; i += stride) {
        Wih16[i] = f2bf(W_ih[i]);
        Whh16[i] = f2bf(W_hh[i]);
    }
    for (int i = idx; i < HID * HID; i += stride) {
        int j = i >> 9, k = i & 511;
        Wch16[i] = f2bf(Wc_w[(long long)j * WCW_LD + 64 + k]);
    }
}

__global__ void leaf_kernel(const int* __restrict__ nt, const float* __restrict__ Pe,
                            u16* __restrict__ h16) {
    int e = blockIdx.x * blockDim.x + threadIdx.x;
    int i = e >> 6, c = e & 63;
    int tv = nt[4681 + i];
    const float4* src = (const float4*)(Pe + (long long)tv * HID + c * 8);
    float4 a = src[0], b = src[1];
    uint4 v;
    v.x = (unsigned)f2bf(tanhf(a.x)) | ((unsigned)f2bf(tanhf(a.y)) << 16);
    v.y = (unsigned)f2bf(tanhf(a.z)) | ((unsigned)f2bf(tanhf(a.w)) << 16);
    v.z = (unsigned)f2bf(tanhf(b.x)) | ((unsigned)f2bf(tanhf(b.y)) << 16);
    v.w = (unsigned)f2bf(tanhf(b.z)) | ((unsigned)f2bf(tanhf(b.w)) << 16);
    *(uint4*)(h16 + (long long)i * HID + c * 8) = v;
}

// ---------------------------------------------------------------------------
// Gx = child16 @ Wih16^T + b_ih ;  C is [M x 1536], fp32 or bf16 out.
// grid (ceil(M/64), 24), block 256
__global__ __launch_bounds__(256, 2)
void gx_gemm(const u16* __restrict__ A, const u16* __restrict__ Wih16,
             const float* __restrict__ b_ih,
             float* __restrict__ gxf, u16* __restrict__ gx16, int M) {
    __shared__ __align__(16) uint8_t sm[2][8192];
    int tid = threadIdx.x;
    int r0 = blockIdx.x * 64, j0 = blockIdx.y * 64;
    int lane = tid & 63, w = tid >> 6, wr = w >> 1, wc = w & 1;

    f32x4 acc[2][2];
#pragma unroll
    for (int i = 0; i < 2; ++i)
#pragma unroll
        for (int j = 0; j < 2; ++j) acc[i][j] = (f32x4){0.f, 0.f, 0.f, 0.f};

    for (int kt = 0; kt < 8; ++kt) {
        int k0 = kt * 64;
        stage_tile(sm[0], A, r0, M, HID, k0, tid);
        stage_tile(sm[1], Wih16, j0, 1 << 30, HID, k0, tid);
        __syncthreads();
#pragma unroll
        for (int s = 0; s < 2; ++s) {
            int kb = s * 64 + ((lane >> 4) << 4);
            bf16x8 a0 = read_frag(sm[0], wr * 32 + (lane & 15), kb);
            bf16x8 a1 = read_frag(sm[0], wr * 32 + 16 + (lane & 15), kb);
#pragma unroll
            for (int jf = 0; jf < 2; ++jf) {
                bf16x8 b = read_frag(sm[1], wc * 32 + jf * 16 + (lane & 15), kb);
                acc[0][jf] = __builtin_amdgcn_mfma_f32_16x16x32_bf16(a0, b, acc[0][jf], 0, 0, 0);
                acc[1][jf] = __builtin_amdgcn_mfma_f32_16x16x32_bf16(a1, b, acc[1][jf], 0, 0, 0);
            }
        }
        __syncthreads();
    }

#pragma unroll
    for (int i = 0; i < 2; ++i) {
#pragma unroll
        for (int jf = 0; jf < 2; ++jf) {
            int jj = j0 + wc * 32 + jf * 16 + (lane & 15);
            float bias = b_ih[jj];
#pragma unroll
            for (int q = 0; q < 4; ++q) {
                int row = r0 + wr * 32 + i * 16 + (lane >> 4) * 4 + q;
                if (row >= M) continue;
                float v = acc[i][jf][q] + bias;
                if (gxf) gxf[(long long)row * 1536 + jj] = v;
                else     gx16[(long long)row * 1536 + jj] = f2bf(v);
            }
        }
    }
}

// ---------------------------------------------------------------------------
// h-side GRU step (x-side hoisted into Gx): 3 gate GEMMs + update.
// grid (ceil(n/64), 8), block 256, LDS 32 KB
__global__ __launch_bounds__(256, 4)
void gru_step_h(const float* __restrict__ gxf, const u16* __restrict__ gx16, int t,
                const float* __restrict__ hsrc_f, const u16* __restrict__ hsrc16,
                float* __restrict__ hdst_f, u16* __restrict__ hdst16,
                const u16* __restrict__ Whh16, const float* __restrict__ b_hh,
                int n, int has_h) {
    __shared__ __align__(16) uint8_t sm[4][8192];   // Ah, Bhh[3]
    int tid = threadIdx.x;
    int p0 = blockIdx.x * 64, j0 = blockIdx.y * 64;
    int lane = tid & 63, w = tid >> 6, wr = w >> 1, wc = w & 1;

    f32x4 acc[3][2][2];
#pragma unroll
    for (int g = 0; g < 3; ++g)
#pragma unroll
        for (int i = 0; i < 2; ++i)
#pragma unroll
            for (int j = 0; j < 2; ++j) acc[g][i][j] = (f32x4){0.f, 0.f, 0.f, 0.f};

    if (has_h) {
        for (int kt = 0; kt < 8; ++kt) {
            int k0 = kt * 64;
            stage_tile(sm[0], hsrc16, p0, n, HID, k0, tid);
#pragma unroll
            for (int g = 0; g < 3; ++g)
                stage_tile(sm[1 + g], Whh16 + (long long)g * HID * HID, j0, 1 << 30, HID, k0, tid);
            __syncthreads();
#pragma unroll
            for (int s = 0; s < 2; ++s) {
                int kb = s * 64 + ((lane >> 4) << 4);
                bf16x8 a0 = read_frag(sm[0], wr * 32 + (lane & 15), kb);
                bf16x8 a1 = read_frag(sm[0], wr * 32 + 16 + (lane & 15), kb);
#pragma unroll
                for (int g = 0; g < 3; ++g) {
#pragma unroll
                    for (int jf = 0; jf < 2; ++jf) {
                        bf16x8 b = read_frag(sm[1 + g], wc * 32 + jf * 16 + (lane & 15), kb);
                        acc[g][0][jf] = __builtin_amdgcn_mfma_f32_16x16x32_bf16(a0, b, acc[g][0][jf], 0, 0, 0);
                        acc[g][1][jf] = __builtin_amdgcn_mfma_f32_16x16x32_bf16(a1, b, acc[g][1][jf], 0, 0, 0);
                    }
                }
            }
            __syncthreads();
        }
    }

#pragma unroll
    for (int i = 0; i < 2; ++i) {
#pragma unroll
        for (int jf = 0; jf < 2; ++jf) {
            int jj = j0 + wc * 32 + jf * 16 + (lane & 15);
            float bhr = b_hh[jj], bhz = b_hh[HID + jj], bhn = b_hh[2 * HID + jj];
#pragma unroll
            for (int q = 0; q < 4; ++q) {
                int p = p0 + wr * 32 + i * 16 + (lane >> 4) * 4 + q;
                if (p >= n) continue;
                long long gb = ((long long)(p * 8 + t)) * 1536 + jj;
                float xr, xz, xn;
                if (gxf) { xr = gxf[gb]; xz = gxf[gb + 512]; xn = gxf[gb + 1024]; }
                else     { xr = bf2f(gx16[gb]); xz = bf2f(gx16[gb + 512]); xn = bf2f(gx16[gb + 1024]); }
                float hr = acc[0][i][jf][q] + bhr;
                float hz = acc[1][i][jf][q] + bhz;
                float hn = acc[2][i][jf][q] + bhn;
                float r = sigm(xr + hr), z = sigm(xz + hz);
                float cand = tanhf(xn + r * hn);
                float hp = has_h ? hsrc_f[(long long)p * HID + jj] : 0.f;
                float hnew = (1.f - z) * cand + z * hp;
                hdst_f[(long long)p * HID + jj] = hnew;
                hdst16[(long long)p * HID + jj] = f2bf(hnew);
            }
        }
    }
}

// ---------------------------------------------------------------------------
// Fallback: fused 6-gate GRU step (x-side not hoisted). Same as round-2 kernel.
__global__ __launch_bounds__(256, 2)
void gru_step_full(const u16* __restrict__ child, int t,
                   const float* __restrict__ hsrc_f, const u16* __restrict__ hsrc16,
                   float* __restrict__ hdst_f, u16* __restrict__ hdst16,
                   const u16* __restrict__ Wih16, const u16* __restrict__ Whh16,
                   const float* __restrict__ b_ih, const float* __restrict__ b_hh,
                   int n, int has_h) {
    __shared__ __align__(16) uint8_t sm[8][8192];
    int tid = threadIdx.x;
    int p0 = blockIdx.x * 64, j0 = blockIdx.y * 64;
    int lane = tid & 63, w = tid >> 6, wr = w >> 1, wc = w & 1;

    f32x4 acc[6][2][2];
#pragma unroll
    for (int g = 0; g < 6; ++g)
#pragma unroll
        for (int i = 0; i < 2; ++i)
#pragma unroll
            for (int j = 0; j < 2; ++j) acc[g][i][j] = (f32x4){0.f, 0.f, 0.f, 0.f};

    for (int kt = 0; kt < 8; ++kt) {
        int k0 = kt * 64;
        stage_tile(sm[0], child + t * HID, p0, n, 8 * HID, k0, tid);
        if (has_h) stage_tile(sm[1], hsrc16, p0, n, HID, k0, tid);
#pragma unroll
        for (int g = 0; g < 3; ++g) {
            stage_tile(sm[2 + g], Wih16 + (long long)g * HID * HID, j0, 1 << 30, HID, k0, tid);
            if (has_h) stage_tile(sm[5 + g], Whh16 + (long long)g * HID * HID, j0, 1 << 30, HID, k0, tid);
        }
        __syncthreads();
#pragma unroll
        for (int s = 0; s < 2; ++s) {
            int kb = s * 64 + ((lane >> 4) << 4);
            bf16x8 ax0 = read_frag(sm[0], wr * 32 + (lane & 15), kb);
            bf16x8 ax1 = read_frag(sm[0], wr * 32 + 16 + (lane & 15), kb);
#pragma unroll
            for (int g = 0; g < 3; ++g) {
#pragma unroll
                for (int j = 0; j < 2; ++j) {
                    bf16x8 b = read_frag(sm[2 + g], wc * 32 + j * 16 + (lane & 15), kb);
                    acc[g][0][j] = __builtin_amdgcn_mfma_f32_16x16x32_bf16(ax0, b, acc[g][0][j], 0, 0, 0);
                    acc[g][1][j] = __builtin_amdgcn_mfma_f32_16x16x32_bf16(ax1, b, acc[g][1][j], 0, 0, 0);
                }
            }
            if (has_h) {
                bf16x8 ah0 = read_frag(sm[1], wr * 32 + (lane & 15), kb);
                bf16x8 ah1 = read_frag(sm[1], wr * 32 + 16 + (lane & 15), kb);
#pragma unroll
                for (int g = 0; g < 3; ++g) {
#pragma unroll
                    for (int j = 0; j < 2; ++j) {
                        bf16x8 b = read_frag(sm[5 + g], wc * 32 + j * 16 + (lane & 15), kb);
                        acc[3 + g][0][j] = __builtin_amdgcn_mfma_f32_16x16x32_bf16(ah0, b, acc[3 + g][0][j], 0, 0, 0);
                        acc[3 + g][1][j] = __builtin_amdgcn_mfma_f32_16x16x32_bf16(ah1, b, acc[3 + g][1][j], 0, 0, 0);
                    }
                }
            }
        }
        __syncthreads();
    }

#pragma unroll
    for (int i = 0; i < 2; ++i) {
#pragma unroll
        for (int j = 0; j < 2; ++j) {
            int jj = j0 + wc * 32 + j * 16 + (lane & 15);
            float bir = b_ih[jj], biz = b_ih[HID + jj], bin_ = b_ih[2 * HID + jj];
            float bhr = b_hh[jj], bhz = b_hh[HID + jj], bhn = b_hh[2 * HID + jj];
#pragma unroll
            for (int q = 0; q < 4; ++q) {
                int p = p0 + wr * 32 + i * 16 + (lane >> 4) * 4 + q;
                if (p >= n) continue;
                float r = sigm(acc[0][i][j][q] + bir + acc[3][i][j][q] + bhr);
                float z = sigm(acc[1][i][j][q] + biz + acc[4][i][j][q] + bhz);
                float cand = tanhf(acc[2][i][j][q] + bin_ + r * (acc[5][i][j][q] + bhn));
                float hp = has_h ? hsrc_f[(long long)p * HID + jj] : 0.f;
                float hnew = (1.f - z) * cand + z * hp;
                hdst_f[(long long)p * HID + jj] = hnew;
                hdst16[(long long)p * HID + jj] = f2bf(hnew);
            }
        }
    }
}

// ---------------------------------------------------------------------------
__global__ __launch_bounds__(256, 2)
void combine_mfma(const u16* __restrict__ enc16, const u16* __restrict__ Wch16,
                  const int* __restrict__ nt, int off, const float* __restrict__ Pe,
                  u16* __restrict__ out16, float* __restrict__ outf, int n) {
    __shared__ __align__(16) uint8_t sm[2][8192];
    int tid = threadIdx.x;
    int p0 = blockIdx.x * 64, j0 = blockIdx.y * 64;
    int lane = tid & 63, w = tid >> 6, wr = w >> 1, wc = w & 1;

    f32x4 acc[2][2];
#pragma unroll
    for (int i = 0; i < 2; ++i)
#pragma unroll
        for (int j = 0; j < 2; ++j) acc[i][j] = (f32x4){0.f, 0.f, 0.f, 0.f};

    for (int kt = 0; kt < 8; ++kt) {
        int k0 = kt * 64;
        stage_tile(sm[0], enc16, p0, n, HID, k0, tid);
        stage_tile(sm[1], Wch16, j0, 1 << 30, HID, k0, tid);
        __syncthreads();
#pragma unroll
        for (int s = 0; s < 2; ++s) {
            int kb = s * 64 + ((lane >> 4) << 4);
            bf16x8 a0 = read_frag(sm[0], wr * 32 + (lane & 15), kb);
            bf16x8 a1 = read_frag(sm[0], wr * 32 + 16 + (lane & 15), kb);
#pragma unroll
            for (int j = 0; j < 2; ++j) {
                bf16x8 b = read_frag(sm[1], wc * 32 + j * 16 + (lane & 15), kb);
                acc[0][j] = __builtin_amdgcn_mfma_f32_16x16x32_bf16(a0, b, acc[0][j], 0, 0, 0);
                acc[1][j] = __builtin_amdgcn_mfma_f32_16x16x32_bf16(a1, b, acc[1][j], 0, 0, 0);
            }
        }
        __syncthreads();
    }

#pragma unroll
    for (int i = 0; i < 2; ++i) {
#pragma unroll
        for (int j = 0; j < 2; ++j) {
            int jj = j0 + wc * 32 + j * 16 + (lane & 15);
#pragma unroll
            for (int q = 0; q < 4; ++q) {
                int p = p0 + wr * 32 + i * 16 + (lane >> 4) * 4 + q;
                if (p >= n) continue;
                int tv = nt[off + p];
                float v = tanhf(Pe[(long long)tv * HID + jj] + acc[i][j][q]);
                out16[(long long)p * HID + jj] = f2bf(v);
                if (outf) outf[(long long)p * HID + jj] = v;
            }
        }
    }
}

// ---------------------------------------------------------------------------
extern "C" void kernel_launch(void* const* d_in, const int* in_sizes, int n_in,
                              void* d_out, int out_size, void* d_ws, size_t ws_size,
                              hipStream_t stream) {
    const int*   nt   = (const int*)d_in[0];
    const float* emb  = (const float*)d_in[1];
    const float* Wc_w = (const float*)d_in[2];
    const float* Wc_b = (const float*)d_in[3];
    const float* W_ih = (const float*)d_in[4];
    const float* W_hh = (const float*)d_in[5];
    const float* b_ih = (const float*)d_in[6];
    const float* b_hh = (const float*)d_in[7];

    uint8_t* p = (uint8_t*)d_ws;
    u16*   cbA   = (u16*)p;   p += (size_t)32768 * HID * 2;
    u16*   cbB   = (u16*)p;   p += (size_t)4096 * HID * 2;
    float* hwfA  = (float*)p; p += (size_t)4096 * HID * 4;
    float* hwfB  = (float*)p; p += (size_t)4096 * HID * 4;
    u16*   hw16A = (u16*)p;   p += (size_t)4096 * HID * 2;
    u16*   hw16B = (u16*)p;   p += (size_t)4096 * HID * 2;
    u16*   Wih16 = (u16*)p;   p += (size_t)3 * HID * HID * 2;
    u16*   Whh16 = (u16*)p;   p += (size_t)3 * HID * HID * 2;
    u16*   Wch16 = (u16*)p;   p += (size_t)HID * HID * 2;
    float* Pe    = (float*)p; p += (size_t)20 * HID * 4;
    uint8_t* gxbuf = p;   // Gx tail buffer
    size_t base = (size_t)(p - (uint8_t*)d_ws);

    // mode selection on available workspace (deterministic host branch)
    // mode 0: fp32 Gx all levels (needs 192 MB tail)
    // mode 1: bf16 Gx at level 4, fp32 below (needs 96 MB tail)
    // mode 2: no hoist at level 4, fp32 Gx below (needs 24 MB tail)
    int mode;
    if (ws_size >= base + (size_t)32768 * 1536 * 4)      mode = 0;
    else if (ws_size >= base + (size_t)32768 * 1536 * 2) mode = 1;
    else                                                 mode = 2;

    conv_w_kernel<<<1024, 256, 0, stream>>>(W_ih, W_hh, Wc_w, Wih16, Whh16, Wch16);
    pe_kernel<<<20, 512, 0, stream>>>(emb, Wc_w, Wc_b, Pe);
    leaf_kernel<<<8192, 256, 0, stream>>>(nt, Pe, cbA);

    const int sizes[5] = {1, 8, 64, 512, 4096};
    const int offs[5]  = {0, 1, 9, 73, 585};

    const u16* child = cbA;
    for (int d = 4; d >= 0; --d) {
        int n = sizes[d];
        int M = n * 8;
        bool hoist = (d < 4) || (mode < 2);
        bool gx_is_f32 = (d < 4) || (mode == 0);
        float* gxf  = gx_is_f32 ? (float*)gxbuf : (float*)0;
        u16*   gx16 = gx_is_f32 ? (u16*)0       : (u16*)gxbuf;

        if (hoist) {
            dim3 ggrid((M + 63) / 64, 24);
            gx_gemm<<<ggrid, 256, 0, stream>>>(child, Wih16, b_ih, gxf, gx16, M);
        }
        dim3 sgrid((n + 63) / 64, 8);
        for (int t = 0; t < 8; ++t) {
            const float* sf  = (t & 1) ? hwfA : hwfB;
            const u16*   s16 = (t & 1) ? hw16A : hw16B;
            float*       df  = (t & 1) ? hwfB : hwfA;
            u16*         d16 = (t & 1) ? hw16B : hw16A;
            if (hoist)
                gru_step_h<<<sgrid, 256, 0, stream>>>(gxf, gx16, t, sf, s16, df, d16,
                                                      Whh16, b_hh, n, t > 0);
            else
                gru_step_full<<<sgrid, 256, 0, stream>>>(child, t, sf, s16, df, d16,
                                                         Wih16, Whh16, b_ih, b_hh, n, t > 0);
        }
        u16* cdst = (d & 1) ? cbA : cbB;
        combine_mfma<<<sgrid, 256, 0, stream>>>(hw16B, Wch16, nt, offs[d], Pe, cdst,
                                                (d == 0) ? (float*)d_out : (float*)0, n);
        child = cdst;
    }
}